// Round 7
// baseline (953.871 us; speedup 1.0000x reference)
//
#include <hip/hip_runtime.h>
#include <math.h>

// inputs [32,64,64,64] f32, embedding [1024,64] f32
#define N_ROWS 131072
#define D      64
#define K_EMB  1024
#define M_TILE 128          // rows per K1 block (4 waves x 32)
#define KC     64           // codes per staged chunk
#define ESTR   72           // padded row stride (ushorts) in esplit/LDS
#define MARGIN_M 1e-5f      // m=dot-en/2 units (2e-5 distance); split-bf16 err ~3e-6

// Output layout (floats): q_st | q_orig | perplexity | encodings
#define Q_ST_OFF 0
#define Q_OR_OFF 8388608
#define PERP_OFF 16777216
#define ENC_OFF  16777217   // odd -> encodings region only 4B-aligned
// float4 slots over out: [0,2097152) q_st | [2097152,4194304) q_or |
// 4194304 = {perp, enc0..2} | (4194304,37748736) enc | + tail scalar enc[last]
#define NFULL4 37748736

// ws layout:
#define WS_COUNTS  0        // uint[1024]
#define WS_FLAGCNT 4096     // uint
#define WS_ENORM   8192     // float[1024]
#define WS_BKS     16384    // int[131072]
#define WS_ESPLIT  540672   // ushort[16 chunks][2 halves][64 rows][72] = 294912 B
#define WS_FLAGS   835584   // int[...]
#define WS_NEEDED  1048576

typedef __attribute__((ext_vector_type(8)))  short bf16x8;
typedef __attribute__((ext_vector_type(16))) float f32x16;

__device__ __forceinline__ unsigned short f2bf_rne(float f) {
    unsigned int u = __float_as_uint(f);
    unsigned int r = u + 0x7fffu + ((u >> 16) & 1u);
    return (unsigned short)(r >> 16);
}
__device__ __forceinline__ float bf2f(unsigned short h) {
    return __uint_as_float(((unsigned int)h) << 16);
}

// ---------- prep: e-norms + bf16 hi/lo split of embedding (once) ----------
__global__ __launch_bounds__(256) void prep_kernel(const float* __restrict__ emb,
                                                   float* __restrict__ enorm,
                                                   unsigned short* __restrict__ esplit) {
    int k = blockIdx.x * 256 + threadIdx.x;           // code row 0..1023
    if (k >= K_EMB) return;
    const float4* row = reinterpret_cast<const float4*>(emb + (size_t)k * D);
    unsigned short* hb = esplit + (size_t)(k >> 6) * (2 * 64 * ESTR) + (k & 63) * ESTR;
    unsigned short* lb = hb + 64 * ESTR;
    float s = 0.f;
#pragma unroll
    for (int i = 0; i < 16; ++i) {
        float4 v = row[i];
        s = fmaf(v.x, v.x, s); s = fmaf(v.y, v.y, s);
        s = fmaf(v.z, v.z, s); s = fmaf(v.w, v.w, s);
        ushort4 h, l;
        h.x = f2bf_rne(v.x); l.x = f2bf_rne(v.x - bf2f(h.x));
        h.y = f2bf_rne(v.y); l.y = f2bf_rne(v.y - bf2f(h.y));
        h.z = f2bf_rne(v.z); l.z = f2bf_rne(v.z - bf2f(h.z));
        h.w = f2bf_rne(v.w); l.w = f2bf_rne(v.w - bf2f(h.w));
        *reinterpret_cast<ushort4*>(hb + i * 4) = h;
        *reinterpret_cast<ushort4*>(lb + i * 4) = l;
    }
    enorm[k] = s;
}

// ---------- K1: MFMA argmin -> bks + counts + ambiguity flags ----------
__global__ __launch_bounds__(256) void vq_argmin(const float* __restrict__ in,
                                                 const unsigned short* __restrict__ esplit,
                                                 const float* __restrict__ enorm32,
                                                 unsigned int* __restrict__ counts,
                                                 unsigned int* __restrict__ flagcount,
                                                 int* __restrict__ flaglist,
                                                 int flagcap,
                                                 int* __restrict__ bks_g) {
    __shared__ __align__(16) unsigned short EHL[2][64][ESTR];  // [hi/lo][code][dim]
    __shared__ __align__(16) float en_s[K_EMB];
    __shared__ int bks_s[M_TILE];

    const int tid  = threadIdx.x;
    const int lane = tid & 63;
    const int w    = tid >> 6;         // wave 0..3
    const int hl   = lane >> 5;        // k-half select
    const int l31  = lane & 31;
    const int base = blockIdx.x * M_TILE;
    const int wrow = w * 32;

    // stage e-norms
    {
        float4 v = *reinterpret_cast<const float4*>(enorm32 + tid * 4);
        *reinterpret_cast<float4*>(&en_s[tid * 4]) = v;
    }

    // A fragments direct from global: row = base+wrow+l31, k-seg = kb*16 + hl*8
    bf16x8 AH[4], AL[4];
    {
        const float* xrow = in + (size_t)(base + wrow + l31) * D + hl * 8;
#pragma unroll
        for (int kb = 0; kb < 4; ++kb) {
            float4 a = *reinterpret_cast<const float4*>(xrow + kb * 16);
            float4 b = *reinterpret_cast<const float4*>(xrow + kb * 16 + 4);
            float f[8] = {a.x, a.y, a.z, a.w, b.x, b.y, b.z, b.w};
            union { bf16x8 v; unsigned short u[8]; } H, L;
#pragma unroll
            for (int j = 0; j < 8; ++j) {
                H.u[j] = f2bf_rne(f[j]);
                L.u[j] = f2bf_rne(f[j] - bf2f(H.u[j]));
            }
            AH[kb] = H.v; AL[kb] = L.v;
        }
    }

    float b1[16], b2[16]; int k1[16];
#pragma unroll
    for (int r = 0; r < 16; ++r) { b1[r] = -1e30f; b2[r] = -1e30f; k1[r] = 0; }

    // T14 staging: load chunk to regs early, ds_write late; single LDS buffer
    uint4 st[5];
    const uint4* src0 = reinterpret_cast<const uint4*>(esplit);
    // chunk ch occupies 1152 uint4 at offset ch*1152
#pragma unroll
    for (int i = 0; i < 5; ++i) {
        int idx = i * 256 + tid;
        if (idx < 1152) st[i] = src0[idx];
    }

#pragma unroll 1
    for (int ch = 0; ch < K_EMB / KC; ++ch) {
        {   // write staged chunk into LDS
            uint4* d = reinterpret_cast<uint4*>(&EHL[0][0][0]);
#pragma unroll
            for (int i = 0; i < 5; ++i) {
                int idx = i * 256 + tid;
                if (idx < 1152) d[idx] = st[i];
            }
        }
        __syncthreads();
        if (ch < 15) {   // prefetch next chunk (completes under compute)
            const uint4* s = src0 + (ch + 1) * 1152;
#pragma unroll
            for (int i = 0; i < 5; ++i) {
                int idx = i * 256 + tid;
                if (idx < 1152) st[i] = s[idx];
            }
        }

#pragma unroll 1
        for (int sub = 0; sub < 2; ++sub) {
            const unsigned short* eh = &EHL[0][sub * 32 + l31][hl * 8];
            const unsigned short* el = &EHL[1][sub * 32 + l31][hl * 8];
            bf16x8 BH[4], BL[4];
#pragma unroll
            for (int kb = 0; kb < 4; ++kb) {
                BH[kb] = *reinterpret_cast<const bf16x8*>(eh + kb * 16);
                BL[kb] = *reinterpret_cast<const bf16x8*>(el + kb * 16);
            }
            f32x16 acc = {};
#pragma unroll
            for (int kb = 0; kb < 4; ++kb)
                acc = __builtin_amdgcn_mfma_f32_32x32x16_bf16(AH[kb], BH[kb], acc, 0, 0, 0);
#pragma unroll
            for (int kb = 0; kb < 4; ++kb)
                acc = __builtin_amdgcn_mfma_f32_32x32x16_bf16(AH[kb], BL[kb], acc, 0, 0, 0);
#pragma unroll
            for (int kb = 0; kb < 4; ++kb)
                acc = __builtin_amdgcn_mfma_f32_32x32x16_bf16(AL[kb], BH[kb], acc, 0, 0, 0);

            int kg = ch * KC + sub * 32 + l31;          // this lane's code (column)
            float mh = 0.5f * en_s[kg];
#pragma unroll
            for (int r = 0; r < 16; ++r) {
                float s = acc[r] - mh;                   // maximize x.e - ||e||^2/2
                if (s > b1[r]) { b2[r] = b1[r]; b1[r] = s; k1[r] = kg; }
                else if (s > b2[r]) b2[r] = s;
            }
        }
        __syncthreads();
    }

    // reduce (b1,k1,b2) across the 32 column-lanes
#pragma unroll
    for (int r = 0; r < 16; ++r) {
        float v = b1[r], v2 = b2[r]; int kk = k1[r];
#pragma unroll
        for (int off = 16; off >= 1; off >>= 1) {
            float ov  = __shfl_xor(v,  off, 64);
            int   ok  = __shfl_xor(kk, off, 64);
            float ov2 = __shfl_xor(v2, off, 64);
            bool win = (ov > v) || (ov == v && ok < kk);
            float loser = win ? v : ov;
            v2 = fmaxf(fmaxf(v2, ov2), loser);
            if (win) { v = ov; kk = ok; }
        }
        if (l31 == 0) {
            int row = wrow + (r & 3) + 8 * (r >> 2) + 4 * hl;  // C-layout row
            bks_s[row] = kk;
            if (v - v2 < MARGIN_M) {
                int pos = (int)atomicAdd(flagcount, 1u);
                if (pos < flagcap) flaglist[pos] = base + row;
            }
        }
    }
    __syncthreads();
    if (tid < M_TILE) {
        int kk = bks_s[tid];
        bks_g[base + tid] = kk;
        atomicAdd(&counts[kk], 1u);
    }
}

// ---------- K2: single-pass computed output writer (pure streaming) ----------
__global__ __launch_bounds__(256) void vq_writer(const float* __restrict__ emb,
                                                 const int* __restrict__ bks_g,
                                                 float* __restrict__ out) {
    const int tid = threadIdx.x;
    const float4* embF4 = reinterpret_cast<const float4*>(emb);
    float4* outF4 = reinterpret_cast<float4*>(out);
    // 2048 blocks x 256 threads x 72 iters covers all NFULL4 full float4 slots
#pragma unroll 1
    for (int i = 0; i < 72; ++i) {
        int f4 = blockIdx.x * (256 * 72) + i * 256 + tid;
        if (f4 >= NFULL4) continue;
        if (f4 < 4194304) {                       // q_st / q_orig
            int q = (f4 < 2097152) ? f4 : f4 - 2097152;
            int row = q >> 4, c4 = q & 15;
            outF4[f4] = embF4[(size_t)bks_g[row] * 16 + c4];
        } else if (f4 == 4194304) {               // perp (skip) + enc[0..2] + tail scalar
            int k0 = bks_g[0];
            out[ENC_OFF + 0] = (k0 == 0) ? 1.f : 0.f;
            out[ENC_OFF + 1] = (k0 == 1) ? 1.f : 0.f;
            out[ENC_OFF + 2] = (k0 == 2) ? 1.f : 0.f;
            out[(size_t)ENC_OFF + 134217727] = (bks_g[N_ROWS - 1] == 1023) ? 1.f : 0.f;
        } else {                                  // encodings, aligned float4
            int g0 = f4 * 4 - ENC_OFF;            // >= 3
            int rA = g0 >> 10;
            int rB = (g0 + 3) >> 10;
            int kA = bks_g[rA];
            int kB = (rB != rA) ? bks_g[rB] : kA;
            float4 v;
            v.x = ((( g0      >> 10) == rA ? kA : kB) == ( g0      & 1023)) ? 1.f : 0.f;
            v.y = ((((g0 + 1) >> 10) == rA ? kA : kB) == ((g0 + 1) & 1023)) ? 1.f : 0.f;
            v.z = ((((g0 + 2) >> 10) == rA ? kA : kB) == ((g0 + 2) & 1023)) ? 1.f : 0.f;
            v.w = ((((g0 + 3) >> 10) == rA ? kA : kB) == ((g0 + 3) & 1023)) ? 1.f : 0.f;
            outF4[f4] = v;
        }
    }
}

// ---------- K3: exact fp64 rescore of flagged rows; patches outputs ----------
__global__ __launch_bounds__(256) void rescore_kernel(const float* __restrict__ in,
                                                      const float* __restrict__ emb,
                                                      const unsigned int* __restrict__ flagcount,
                                                      const int* __restrict__ flaglist,
                                                      int flagcap,
                                                      unsigned int* __restrict__ counts,
                                                      int* __restrict__ bks_g,
                                                      float* __restrict__ out) {
    __shared__ __align__(16) float xs[64];
    __shared__ double rv[4];
    __shared__ int    rk[4];

    const int tid = threadIdx.x;
    int nf = (int)*flagcount;
    bool overflow = nf > flagcap;
    int total = overflow ? N_ROWS : nf;

    for (int idx = blockIdx.x; idx < total; idx += gridDim.x) {
        int row = overflow ? idx : flaglist[idx];
        int oldk = bks_g[row];
        if (tid < 16)
            *reinterpret_cast<float4*>(&xs[tid * 4]) =
                reinterpret_cast<const float4*>(in + (size_t)row * D)[tid];
        __syncthreads();

        double bv = 1e300; int bk = 0;
#pragma unroll 1
        for (int c = 0; c < 4; ++c) {
            int k = tid * 4 + c;
            const float4* er = reinterpret_cast<const float4*>(emb + (size_t)k * D);
            double dot = 0.0, en = 0.0;
#pragma unroll 4
            for (int i = 0; i < 16; ++i) {
                float4 ev = er[i];
                float4 xv = *reinterpret_cast<const float4*>(&xs[i * 4]);
                double e0 = ev.x, e1 = ev.y, e2 = ev.z, e3 = ev.w;
                en  = fma(e0, e0, en);  en  = fma(e1, e1, en);
                en  = fma(e2, e2, en);  en  = fma(e3, e3, en);
                dot = fma((double)xv.x, e0, dot); dot = fma((double)xv.y, e1, dot);
                dot = fma((double)xv.z, e2, dot); dot = fma((double)xv.w, e3, dot);
            }
            double s = fma(-2.0, dot, en);
            if (s < bv) { bv = s; bk = k; }       // k ascending -> first index
        }
        const int lane = tid & 63, w = tid >> 6;
        {
            double v = bv; int kk = bk;
#pragma unroll
            for (int off = 32; off >= 1; off >>= 1) {
                double ov = __shfl_xor(v, off, 64);
                int    ok = __shfl_xor(kk, off, 64);
                if (ov < v || (ov == v && ok < kk)) { v = ov; kk = ok; }
            }
            if (lane == 0) { rv[w] = v; rk[w] = kk; }
        }
        __syncthreads();
        if (tid == 0) {
            double v = rv[0]; int kk = rk[0];
#pragma unroll
            for (int x = 1; x < 4; ++x) {
                double ov = rv[x]; int ok = rk[x];
                if (ov < v || (ov == v && ok < kk)) { v = ov; kk = ok; }
            }
            if (kk != oldk) {
                bks_g[row] = kk;
                out[ENC_OFF + (size_t)row * K_EMB + oldk] = 0.0f;
                out[ENC_OFF + (size_t)row * K_EMB + kk]   = 1.0f;
                atomicAdd(&counts[oldk], (unsigned int)-1);
                atomicAdd(&counts[kk], 1u);
                const float4* er = reinterpret_cast<const float4*>(emb + (size_t)kk * D);
                float4* o1 = reinterpret_cast<float4*>(out + Q_ST_OFF + (size_t)row * D);
                float4* o2 = reinterpret_cast<float4*>(out + Q_OR_OFF + (size_t)row * D);
#pragma unroll
                for (int i = 0; i < 16; ++i) { float4 vv = er[i]; o1[i] = vv; o2[i] = vv; }
            }
        }
        __syncthreads();
    }
}

__global__ __launch_bounds__(1024) void perp_kernel(const unsigned int* __restrict__ counts,
                                                    float* __restrict__ out_perp) {
    const int k = threadIdx.x;
    double p = (double)counts[k] * (1.0 / (double)N_ROWS);
    double t = p * log(p + 1e-10);
#pragma unroll
    for (int off = 32; off >= 1; off >>= 1) t += __shfl_down(t, off, 64);
    __shared__ double red[16];
    if ((k & 63) == 0) red[k >> 6] = t;
    __syncthreads();
    if (k < 16) {
        double s = red[k];
#pragma unroll
        for (int off = 8; off >= 1; off >>= 1) s += __shfl_down(s, off, 16);
        if (k == 0) out_perp[0] = (float)exp(-s);
    }
}

// ================= fallback (tiny ws): round-5 monolith =================
__global__ __launch_bounds__(256) void enorm32_kernel(const float* __restrict__ emb,
                                                      float* __restrict__ enorm) {
    int k = blockIdx.x * 256 + threadIdx.x;
    const float4* row = reinterpret_cast<const float4*>(emb + (size_t)k * D);
    float s = 0.f;
#pragma unroll
    for (int i = 0; i < 16; ++i) {
        float4 v = row[i];
        s = fmaf(v.x, v.x, s); s = fmaf(v.y, v.y, s);
        s = fmaf(v.z, v.z, s); s = fmaf(v.w, v.w, s);
    }
    enorm[k] = s;
}

__global__ __launch_bounds__(256) void vq_mono(const float* __restrict__ in,
                                               const float* __restrict__ emb,
                                               const float* __restrict__ enorm32,
                                               unsigned int* __restrict__ counts,
                                               float* __restrict__ out) {
    __shared__ __align__(16) unsigned short XH[M_TILE * ESTR];
    __shared__ __align__(16) unsigned short XL[M_TILE * ESTR];
    __shared__ __align__(16) unsigned short EH[128 * ESTR];
    __shared__ __align__(16) unsigned short EL[128 * ESTR];
    __shared__ __align__(16) float en_s[K_EMB];
    __shared__ __align__(16) float xs2[D];
    __shared__ int bks[M_TILE];
    __shared__ int flagl[M_TILE];
    __shared__ int nflag;
    __shared__ double rv[4];
    __shared__ int    rk[4];

    const int tid  = threadIdx.x;
    const int lane = tid & 63;
    const int w    = tid >> 6;
    const int hl   = lane >> 5;
    const int l31  = lane & 31;
    const int base = blockIdx.x * M_TILE;
    const int wrow = w * 32;

    if (tid == 0) nflag = 0;
    {
        float4 v = *reinterpret_cast<const float4*>(enorm32 + tid * 4);
        *reinterpret_cast<float4*>(&en_s[tid * 4]) = v;
    }
    {
        const float4* src = reinterpret_cast<const float4*>(in + (size_t)base * D);
#pragma unroll
        for (int i = 0; i < 8; ++i) {
            int lin = i * 256 + tid;
            float4 v = src[lin];
            int row = lin >> 4, c4 = lin & 15;
            ushort4 h, l;
            h.x = f2bf_rne(v.x); l.x = f2bf_rne(v.x - bf2f(h.x));
            h.y = f2bf_rne(v.y); l.y = f2bf_rne(v.y - bf2f(h.y));
            h.z = f2bf_rne(v.z); l.z = f2bf_rne(v.z - bf2f(h.z));
            h.w = f2bf_rne(v.w); l.w = f2bf_rne(v.w - bf2f(h.w));
            *reinterpret_cast<ushort4*>(&XH[row * ESTR + c4 * 4]) = h;
            *reinterpret_cast<ushort4*>(&XL[row * ESTR + c4 * 4]) = l;
        }
    }
    __syncthreads();

    bf16x8 AH[4], AL[4];
    {
        const unsigned short* xh = &XH[(wrow + l31) * ESTR + hl * 8];
        const unsigned short* xl = &XL[(wrow + l31) * ESTR + hl * 8];
#pragma unroll
        for (int kb = 0; kb < 4; ++kb) {
            AH[kb] = *reinterpret_cast<const bf16x8*>(xh + kb * 16);
            AL[kb] = *reinterpret_cast<const bf16x8*>(xl + kb * 16);
        }
    }

    float b1[16], b2[16]; int k1[16];
#pragma unroll
    for (int r = 0; r < 16; ++r) { b1[r] = 1e30f; b2[r] = 1e30f; k1[r] = 0; }

#pragma unroll 1
    for (int ch = 0; ch < K_EMB / 128; ++ch) {
        __syncthreads();
        {
            const float4* esrc = reinterpret_cast<const float4*>(emb + (size_t)ch * 128 * D);
#pragma unroll
            for (int i = 0; i < 8; ++i) {
                int lin = i * 256 + tid;
                float4 v = esrc[lin];
                int row = lin >> 4, c4 = lin & 15;
                ushort4 h, l;
                h.x = f2bf_rne(v.x); l.x = f2bf_rne(v.x - bf2f(h.x));
                h.y = f2bf_rne(v.y); l.y = f2bf_rne(v.y - bf2f(h.y));
                h.z = f2bf_rne(v.z); l.z = f2bf_rne(v.z - bf2f(h.z));
                h.w = f2bf_rne(v.w); l.w = f2bf_rne(v.w - bf2f(h.w));
                *reinterpret_cast<ushort4*>(&EH[row * ESTR + c4 * 4]) = h;
                *reinterpret_cast<ushort4*>(&EL[row * ESTR + c4 * 4]) = l;
            }
        }
        __syncthreads();

#pragma unroll 1
        for (int sub = 0; sub < 4; ++sub) {
            const unsigned short* eh = &EH[(sub * 32 + l31) * ESTR + hl * 8];
            const unsigned short* el = &EL[(sub * 32 + l31) * ESTR + hl * 8];
            bf16x8 BH[4], BL[4];
#pragma unroll
            for (int kb = 0; kb < 4; ++kb) {
                BH[kb] = *reinterpret_cast<const bf16x8*>(eh + kb * 16);
                BL[kb] = *reinterpret_cast<const bf16x8*>(el + kb * 16);
            }
            f32x16 acc = {};
#pragma unroll
            for (int kb = 0; kb < 4; ++kb)
                acc = __builtin_amdgcn_mfma_f32_32x32x16_bf16(AH[kb], BH[kb], acc, 0, 0, 0);
#pragma unroll
            for (int kb = 0; kb < 4; ++kb)
                acc = __builtin_amdgcn_mfma_f32_32x32x16_bf16(AH[kb], BL[kb], acc, 0, 0, 0);
#pragma unroll
            for (int kb = 0; kb < 4; ++kb)
                acc = __builtin_amdgcn_mfma_f32_32x32x16_bf16(AL[kb], BH[kb], acc, 0, 0, 0);

            int kg = ch * 128 + sub * 32 + l31;
            float en = en_s[kg];
#pragma unroll
            for (int r = 0; r < 16; ++r) {
                float s = fmaf(-2.f, acc[r], en);
                if (s < b1[r]) { b2[r] = b1[r]; b1[r] = s; k1[r] = kg; }
                else if (s < b2[r]) b2[r] = s;
            }
            asm volatile("" ::: "memory");
        }
    }

#pragma unroll
    for (int r = 0; r < 16; ++r) {
        float v = b1[r], v2 = b2[r]; int kk = k1[r];
#pragma unroll
        for (int off = 16; off >= 1; off >>= 1) {
            float ov  = __shfl_xor(v,  off, 64);
            int   ok  = __shfl_xor(kk, off, 64);
            float ov2 = __shfl_xor(v2, off, 64);
            bool win = (ov < v) || (ov == v && ok < kk);
            float loser = win ? v : ov;
            v2 = fminf(fminf(v2, ov2), loser);
            if (win) { v = ov; kk = ok; }
        }
        if (l31 == 0) {
            int row = wrow + (r & 3) + 8 * (r >> 2) + 4 * hl;
            bks[row] = kk;
            if (v2 - v < 2e-5f) { int p = atomicAdd(&nflag, 1); flagl[p] = row; }
        }
    }
    {
        float* ep = out + ENC_OFF + (size_t)base * K_EMB;
        float4 z = make_float4(0.f, 0.f, 0.f, 0.f);
        float4* ap = reinterpret_cast<float4*>(ep + 3);
        for (int i = tid; i < 32767; i += 256) ap[i] = z;
        if (tid == 0) { ep[0] = 0.f; ep[1] = 0.f; ep[2] = 0.f; ep[131071] = 0.f; }
    }
    __syncthreads();

    int nf = nflag;
#pragma unroll 1
    for (int fi = 0; fi < nf; ++fi) {
        int row = flagl[fi];
        if (tid < 16)
            *reinterpret_cast<float4*>(&xs2[tid * 4]) =
                reinterpret_cast<const float4*>(in + (size_t)(base + row) * D)[tid];
        __syncthreads();
        double bv = 1e300; int bk = 0;
#pragma unroll 1
        for (int c = 0; c < 4; ++c) {
            int k = tid * 4 + c;
            const float4* er = reinterpret_cast<const float4*>(emb + (size_t)k * D);
            double dot = 0.0, en = 0.0;
#pragma unroll 4
            for (int i = 0; i < 16; ++i) {
                float4 ev = er[i];
                float4 xv = *reinterpret_cast<const float4*>(&xs2[i * 4]);
                double e0 = ev.x, e1 = ev.y, e2 = ev.z, e3 = ev.w;
                en  = fma(e0, e0, en);  en  = fma(e1, e1, en);
                en  = fma(e2, e2, en);  en  = fma(e3, e3, en);
                dot = fma((double)xv.x, e0, dot); dot = fma((double)xv.y, e1, dot);
                dot = fma((double)xv.z, e2, dot); dot = fma((double)xv.w, e3, dot);
            }
            double s = fma(-2.0, dot, en);
            if (s < bv) { bv = s; bk = k; }
        }
        {
            double v = bv; int kk = bk;
#pragma unroll
            for (int off = 32; off >= 1; off >>= 1) {
                double ov = __shfl_xor(v, off, 64);
                int    ok = __shfl_xor(kk, off, 64);
                if (ov < v || (ov == v && ok < kk)) { v = ov; kk = ok; }
            }
            if (lane == 0) { rv[w] = v; rk[w] = kk; }
        }
        __syncthreads();
        if (tid == 0) {
            double v = rv[0]; int kk = rk[0];
#pragma unroll
            for (int x = 1; x < 4; ++x) {
                double ov = rv[x]; int ok = rk[x];
                if (ov < v || (ov == v && ok < kk)) { v = ov; kk = ok; }
            }
            bks[row] = kk;
        }
        __syncthreads();
    }

    if (tid < M_TILE) {
        int kk = bks[tid];
        atomicAdd(&counts[kk], 1u);
        out[ENC_OFF + (size_t)(base + tid) * K_EMB + kk] = 1.0f;
    }
    {
        int row = tid >> 1;
        int p   = tid & 1;
        int kk  = bks[row];
        const float4* er = reinterpret_cast<const float4*>(emb + (size_t)kk * D);
        float4* o1 = reinterpret_cast<float4*>(out + Q_ST_OFF + (size_t)(base + row) * D);
        float4* o2 = reinterpret_cast<float4*>(out + Q_OR_OFF + (size_t)(base + row) * D);
#pragma unroll
        for (int i = 0; i < 8; ++i) {
            float4 v = er[p * 8 + i];
            o1[p * 8 + i] = v;
            o2[p * 8 + i] = v;
        }
    }
}

extern "C" void kernel_launch(void* const* d_in, const int* in_sizes, int n_in,
                              void* d_out, int out_size, void* d_ws, size_t ws_size,
                              hipStream_t stream) {
    const float* in  = (const float*)d_in[0];
    const float* emb = (const float*)d_in[1];
    float* out = (float*)d_out;
    unsigned int* counts    = (unsigned int*)((char*)d_ws + WS_COUNTS);
    unsigned int* flagcount = (unsigned int*)((char*)d_ws + WS_FLAGCNT);
    float*        enorm32   = (float*)((char*)d_ws + WS_ENORM);

    if (ws_size >= WS_NEEDED) {
        int*            bks_g   = (int*)((char*)d_ws + WS_BKS);
        unsigned short* esplit  = (unsigned short*)((char*)d_ws + WS_ESPLIT);
        int*            flaglist= (int*)((char*)d_ws + WS_FLAGS);
        int flagcap = (int)((ws_size - WS_FLAGS) / 4);
        if (flagcap > N_ROWS) flagcap = N_ROWS;

        hipMemsetAsync(d_ws, 0, 8192, stream);   // counts + flagcount
        prep_kernel<<<4, 256, 0, stream>>>(emb, enorm32, esplit);
        vq_argmin<<<N_ROWS / M_TILE, 256, 0, stream>>>(in, esplit, enorm32, counts,
                                                       flagcount, flaglist, flagcap, bks_g);
        vq_writer<<<2048, 256, 0, stream>>>(emb, bks_g, out);
        rescore_kernel<<<1024, 256, 0, stream>>>(in, emb, flagcount, flaglist, flagcap,
                                                 counts, bks_g, out);
        perp_kernel<<<1, 1024, 0, stream>>>(counts, out + PERP_OFF);
    } else {
        hipMemsetAsync(d_ws, 0, 4096, stream);   // counts
        enorm32_kernel<<<K_EMB / 256, 256, 0, stream>>>(emb, enorm32);
        vq_mono<<<N_ROWS / M_TILE, 256, 0, stream>>>(in, emb, enorm32, counts, out);
        perp_kernel<<<1, 1024, 0, stream>>>(counts, out + PERP_OFF);
    }
}

// Round 8
// 915.887 us; speedup vs baseline: 1.0415x; 1.0415x over previous
//
#include <hip/hip_runtime.h>
#include <math.h>

// inputs [32,64,64,64] f32, embedding [1024,64] f32
#define N_ROWS 131072
#define D      64
#define K_EMB  1024
#define M_TILE 128          // rows per block (4 waves x 32)
#define KC     64           // codes per staged chunk
#define ESTR   72           // padded row stride (ushorts) in esplit/LDS
#define MARGIN_M 1e-5f      // m units (2e-5 distance); split-bf16 err ~3e-6

// Output layout (floats): q_st | q_orig | perplexity | encodings
#define Q_ST_OFF 0
#define Q_OR_OFF 8388608
#define PERP_OFF 16777216
#define ENC_OFF  16777217   // odd -> encodings region only 4B-aligned

// ws layout:
#define WS_COUNTS  0        // uint[1024]
#define WS_FLAGCNT 4096     // uint
#define WS_ENORM   8192     // float[1024]
#define WS_BKS     16384    // int[131072]
#define WS_ESPLIT  540672   // ushort[16 chunks][2 halves][64 rows][72]
#define WS_FLAGS   835584   // int[...]
#define WS_NEEDED  1048576

typedef __attribute__((ext_vector_type(8)))  short bf16x8;
typedef __attribute__((ext_vector_type(16))) float f32x16;

__device__ __forceinline__ unsigned short f2bf_rne(float f) {
    unsigned int u = __float_as_uint(f);
    unsigned int r = u + 0x7fffu + ((u >> 16) & 1u);
    return (unsigned short)(r >> 16);
}
__device__ __forceinline__ float bf2f(unsigned short h) {
    return __uint_as_float(((unsigned int)h) << 16);
}

// ---------- prep: e-norms + bf16 hi/lo split of embedding (once) ----------
__global__ __launch_bounds__(256) void prep_kernel(const float* __restrict__ emb,
                                                   float* __restrict__ enorm,
                                                   unsigned short* __restrict__ esplit) {
    int k = blockIdx.x * 256 + threadIdx.x;           // code row 0..1023
    if (k >= K_EMB) return;
    const float4* row = reinterpret_cast<const float4*>(emb + (size_t)k * D);
    unsigned short* hb = esplit + (size_t)(k >> 6) * (2 * 64 * ESTR) + (k & 63) * ESTR;
    unsigned short* lb = hb + 64 * ESTR;
    float s = 0.f;
#pragma unroll
    for (int i = 0; i < 16; ++i) {
        float4 v = row[i];
        s = fmaf(v.x, v.x, s); s = fmaf(v.y, v.y, s);
        s = fmaf(v.z, v.z, s); s = fmaf(v.w, v.w, s);
        ushort4 h, l;
        h.x = f2bf_rne(v.x); l.x = f2bf_rne(v.x - bf2f(h.x));
        h.y = f2bf_rne(v.y); l.y = f2bf_rne(v.y - bf2f(h.y));
        h.z = f2bf_rne(v.z); l.z = f2bf_rne(v.z - bf2f(h.z));
        h.w = f2bf_rne(v.w); l.w = f2bf_rne(v.w - bf2f(h.w));
        *reinterpret_cast<ushort4*>(hb + i * 4) = h;
        *reinterpret_cast<ushort4*>(lb + i * 4) = l;
    }
    enorm[k] = s;
}

// ---------- fused: MFMA argmin + single-pass computed output writes ----------
__global__ __launch_bounds__(256) void vq_fused(const float* __restrict__ in,
                                                const float* __restrict__ emb,
                                                const unsigned short* __restrict__ esplit,
                                                const float* __restrict__ enorm32,
                                                unsigned int* __restrict__ counts,
                                                unsigned int* __restrict__ flagcount,
                                                int* __restrict__ flaglist,
                                                int flagcap,
                                                int* __restrict__ bks_g,
                                                float* __restrict__ out) {
    __shared__ __align__(16) unsigned short EHL[2][64][ESTR];  // [hi/lo][code][dim]
    __shared__ __align__(16) float en_s[K_EMB];
    __shared__ int bks_s[M_TILE];

    const int tid  = threadIdx.x;
    const int lane = tid & 63;
    const int w    = tid >> 6;         // wave 0..3
    const int hl   = lane >> 5;        // k-half select
    const int l31  = lane & 31;
    const int base = blockIdx.x * M_TILE;
    const int wrow = w * 32;

    // stage e-norms
    {
        float4 v = *reinterpret_cast<const float4*>(enorm32 + tid * 4);
        *reinterpret_cast<float4*>(&en_s[tid * 4]) = v;
    }

    // A fragments direct from global: row = base+wrow+l31, k-seg = kb*16 + hl*8
    bf16x8 AH[4], AL[4];
    {
        const float* xrow = in + (size_t)(base + wrow + l31) * D + hl * 8;
#pragma unroll
        for (int kb = 0; kb < 4; ++kb) {
            float4 a = *reinterpret_cast<const float4*>(xrow + kb * 16);
            float4 b = *reinterpret_cast<const float4*>(xrow + kb * 16 + 4);
            float f[8] = {a.x, a.y, a.z, a.w, b.x, b.y, b.z, b.w};
            union { bf16x8 v; unsigned short u[8]; } H, L;
#pragma unroll
            for (int j = 0; j < 8; ++j) {
                H.u[j] = f2bf_rne(f[j]);
                L.u[j] = f2bf_rne(f[j] - bf2f(H.u[j]));
            }
            AH[kb] = H.v; AL[kb] = L.v;
        }
    }

    float b1[16], b2[16]; int k1[16];
#pragma unroll
    for (int r = 0; r < 16; ++r) { b1[r] = -1e30f; b2[r] = -1e30f; k1[r] = 0; }

    // staging: load chunk to regs early, ds_write late; single LDS buffer
    uint4 st[5];
    const uint4* src0 = reinterpret_cast<const uint4*>(esplit);  // chunk = 1152 uint4
#pragma unroll
    for (int i = 0; i < 5; ++i) {
        int idx = i * 256 + tid;
        if (idx < 1152) st[i] = src0[idx];
    }

#pragma unroll 1
    for (int ch = 0; ch < K_EMB / KC; ++ch) {
        {   // write staged chunk into LDS
            uint4* d = reinterpret_cast<uint4*>(&EHL[0][0][0]);
#pragma unroll
            for (int i = 0; i < 5; ++i) {
                int idx = i * 256 + tid;
                if (idx < 1152) d[idx] = st[i];
            }
        }
        __syncthreads();
        if (ch < 15) {   // prefetch next chunk (completes under compute)
            const uint4* s = src0 + (ch + 1) * 1152;
#pragma unroll
            for (int i = 0; i < 5; ++i) {
                int idx = i * 256 + tid;
                if (idx < 1152) st[i] = s[idx];
            }
        }

#pragma unroll 1
        for (int sub = 0; sub < 2; ++sub) {
            const unsigned short* eh = &EHL[0][sub * 32 + l31][hl * 8];
            const unsigned short* el = &EHL[1][sub * 32 + l31][hl * 8];
            bf16x8 BH[4], BL[4];
#pragma unroll
            for (int kb = 0; kb < 4; ++kb) {
                BH[kb] = *reinterpret_cast<const bf16x8*>(eh + kb * 16);
                BL[kb] = *reinterpret_cast<const bf16x8*>(el + kb * 16);
            }
            f32x16 acc = {};
#pragma unroll
            for (int kb = 0; kb < 4; ++kb)
                acc = __builtin_amdgcn_mfma_f32_32x32x16_bf16(AH[kb], BH[kb], acc, 0, 0, 0);
#pragma unroll
            for (int kb = 0; kb < 4; ++kb)
                acc = __builtin_amdgcn_mfma_f32_32x32x16_bf16(AH[kb], BL[kb], acc, 0, 0, 0);
#pragma unroll
            for (int kb = 0; kb < 4; ++kb)
                acc = __builtin_amdgcn_mfma_f32_32x32x16_bf16(AL[kb], BH[kb], acc, 0, 0, 0);

            int kg = ch * KC + sub * 32 + l31;          // this lane's code (column)
            float mh = 0.5f * en_s[kg];
#pragma unroll
            for (int r = 0; r < 16; ++r) {
                float s = acc[r] - mh;                   // maximize x.e - ||e||^2/2
                if (s > b1[r]) { b2[r] = b1[r]; b1[r] = s; k1[r] = kg; }
                else if (s > b2[r]) b2[r] = s;
            }
        }
        __syncthreads();
    }

    // reduce (b1,k1,b2) across the 32 column-lanes
#pragma unroll
    for (int r = 0; r < 16; ++r) {
        float v = b1[r], v2 = b2[r]; int kk = k1[r];
#pragma unroll
        for (int off = 16; off >= 1; off >>= 1) {
            float ov  = __shfl_xor(v,  off, 64);
            int   ok  = __shfl_xor(kk, off, 64);
            float ov2 = __shfl_xor(v2, off, 64);
            bool win = (ov > v) || (ov == v && ok < kk);
            float loser = win ? v : ov;
            v2 = fmaxf(fmaxf(v2, ov2), loser);
            if (win) { v = ov; kk = ok; }
        }
        if (l31 == 0) {
            int row = wrow + (r & 3) + 8 * (r >> 2) + 4 * hl;  // C-layout row
            bks_s[row] = kk;
            if (v - v2 < MARGIN_M) {
                int pos = (int)atomicAdd(flagcount, 1u);
                if (pos < flagcap) flaglist[pos] = base + row;
            }
        }
    }
    __syncthreads();

    if (tid < M_TILE) {
        int kk = bks_s[tid];
        bks_g[base + tid] = kk;
        atomicAdd(&counts[kk], 1u);
    }

    // ---- q_st / q_orig: 2048 float4 per output, gathered from emb ----
    {
        const float4* embF4 = reinterpret_cast<const float4*>(emb);
        float4* o1 = reinterpret_cast<float4*>(out + Q_ST_OFF + (size_t)base * D);
        float4* o2 = reinterpret_cast<float4*>(out + Q_OR_OFF + (size_t)base * D);
#pragma unroll 1
        for (int i = 0; i < 8; ++i) {
            int f4q = i * 256 + tid;          // 0..2047
            int row = f4q >> 4, c4 = f4q & 15;
            float4 v = embF4[(size_t)bks_s[row] * 16 + c4];
            o1[f4q] = v;
            o2[f4q] = v;
        }
    }

    // ---- encodings: single-pass computed one-hot (region 4B-aligned only) ----
    {
        float* ep = out + ENC_OFF + (size_t)base * K_EMB;   // float idx ≡ 1 (mod 4)
        float4* ap = reinterpret_cast<float4*>(ep + 3);     // 16B-aligned
#pragma unroll 4
        for (int f4e = tid; f4e < 32767; f4e += 256) {
            int g0 = 3 + f4e * 4;                  // local float offset, row=g0>>10
            int lrA = g0 >> 10;
            int lrB = (g0 + 3) >> 10;
            int kA = bks_s[lrA];
            int kB = (lrB != lrA) ? bks_s[lrB] : kA;
            float4 v;
            v.x = ((( g0      >> 10) == lrA ? kA : kB) == ( g0      & 1023)) ? 1.f : 0.f;
            v.y = ((((g0 + 1) >> 10) == lrA ? kA : kB) == ((g0 + 1) & 1023)) ? 1.f : 0.f;
            v.z = ((((g0 + 2) >> 10) == lrA ? kA : kB) == ((g0 + 2) & 1023)) ? 1.f : 0.f;
            v.w = ((((g0 + 3) >> 10) == lrA ? kA : kB) == ((g0 + 3) & 1023)) ? 1.f : 0.f;
            ap[f4e] = v;
        }
        if (tid == 0) {                            // head 3 scalars + tail 1 scalar
            int k0 = bks_s[0];
            ep[0] = (k0 == 0) ? 1.f : 0.f;
            ep[1] = (k0 == 1) ? 1.f : 0.f;
            ep[2] = (k0 == 2) ? 1.f : 0.f;
            ep[131071] = (bks_s[127] == 1023) ? 1.f : 0.f;
        }
    }
}

// ---------- fp64 rescore of flagged rows; patches outputs ----------
__global__ __launch_bounds__(256) void rescore_kernel(const float* __restrict__ in,
                                                      const float* __restrict__ emb,
                                                      const unsigned int* __restrict__ flagcount,
                                                      const int* __restrict__ flaglist,
                                                      int flagcap,
                                                      unsigned int* __restrict__ counts,
                                                      int* __restrict__ bks_g,
                                                      float* __restrict__ out) {
    __shared__ __align__(16) float xs[64];
    __shared__ double rv[4];
    __shared__ int    rk[4];

    const int tid = threadIdx.x;
    int nf = (int)*flagcount;
    bool overflow = nf > flagcap;
    int total = overflow ? N_ROWS : nf;

    for (int idx = blockIdx.x; idx < total; idx += gridDim.x) {
        int row = overflow ? idx : flaglist[idx];
        int oldk = bks_g[row];
        if (tid < 16)
            *reinterpret_cast<float4*>(&xs[tid * 4]) =
                reinterpret_cast<const float4*>(in + (size_t)row * D)[tid];
        __syncthreads();

        double bv = 1e300; int bk = 0;
#pragma unroll 1
        for (int c = 0; c < 4; ++c) {
            int k = tid * 4 + c;
            const float4* er = reinterpret_cast<const float4*>(emb + (size_t)k * D);
            double dot = 0.0, en = 0.0;
#pragma unroll 4
            for (int i = 0; i < 16; ++i) {
                float4 ev = er[i];
                float4 xv = *reinterpret_cast<const float4*>(&xs[i * 4]);
                double e0 = ev.x, e1 = ev.y, e2 = ev.z, e3 = ev.w;
                en  = fma(e0, e0, en);  en  = fma(e1, e1, en);
                en  = fma(e2, e2, en);  en  = fma(e3, e3, en);
                dot = fma((double)xv.x, e0, dot); dot = fma((double)xv.y, e1, dot);
                dot = fma((double)xv.z, e2, dot); dot = fma((double)xv.w, e3, dot);
            }
            double s = fma(-2.0, dot, en);
            if (s < bv) { bv = s; bk = k; }       // k ascending -> first index
        }
        const int lane = tid & 63, w = tid >> 6;
        {
            double v = bv; int kk = bk;
#pragma unroll
            for (int off = 32; off >= 1; off >>= 1) {
                double ov = __shfl_xor(v, off, 64);
                int    ok = __shfl_xor(kk, off, 64);
                if (ov < v || (ov == v && ok < kk)) { v = ov; kk = ok; }
            }
            if (lane == 0) { rv[w] = v; rk[w] = kk; }
        }
        __syncthreads();
        if (tid == 0) {
            double v = rv[0]; int kk = rk[0];
#pragma unroll
            for (int x = 1; x < 4; ++x) {
                double ov = rv[x]; int ok = rk[x];
                if (ov < v || (ov == v && ok < kk)) { v = ov; kk = ok; }
            }
            if (kk != oldk) {
                bks_g[row] = kk;
                out[ENC_OFF + (size_t)row * K_EMB + oldk] = 0.0f;
                out[ENC_OFF + (size_t)row * K_EMB + kk]   = 1.0f;
                atomicAdd(&counts[oldk], (unsigned int)-1);
                atomicAdd(&counts[kk], 1u);
                const float4* er = reinterpret_cast<const float4*>(emb + (size_t)kk * D);
                float4* o1 = reinterpret_cast<float4*>(out + Q_ST_OFF + (size_t)row * D);
                float4* o2 = reinterpret_cast<float4*>(out + Q_OR_OFF + (size_t)row * D);
#pragma unroll
                for (int i = 0; i < 16; ++i) { float4 vv = er[i]; o1[i] = vv; o2[i] = vv; }
            }
        }
        __syncthreads();
    }
}

__global__ __launch_bounds__(1024) void perp_kernel(const unsigned int* __restrict__ counts,
                                                    float* __restrict__ out_perp) {
    const int k = threadIdx.x;
    double p = (double)counts[k] * (1.0 / (double)N_ROWS);
    double t = p * log(p + 1e-10);
#pragma unroll
    for (int off = 32; off >= 1; off >>= 1) t += __shfl_down(t, off, 64);
    __shared__ double red[16];
    if ((k & 63) == 0) red[k >> 6] = t;
    __syncthreads();
    if (k < 16) {
        double s = red[k];
#pragma unroll
        for (int off = 8; off >= 1; off >>= 1) s += __shfl_down(s, off, 16);
        if (k == 0) out_perp[0] = (float)exp(-s);
    }
}

// ================= fallback (tiny ws): round-5 monolith =================
__global__ __launch_bounds__(256) void enorm32_kernel(const float* __restrict__ emb,
                                                      float* __restrict__ enorm) {
    int k = blockIdx.x * 256 + threadIdx.x;
    const float4* row = reinterpret_cast<const float4*>(emb + (size_t)k * D);
    float s = 0.f;
#pragma unroll
    for (int i = 0; i < 16; ++i) {
        float4 v = row[i];
        s = fmaf(v.x, v.x, s); s = fmaf(v.y, v.y, s);
        s = fmaf(v.z, v.z, s); s = fmaf(v.w, v.w, s);
    }
    enorm[k] = s;
}

__global__ __launch_bounds__(256) void vq_mono(const float* __restrict__ in,
                                               const float* __restrict__ emb,
                                               const float* __restrict__ enorm32,
                                               unsigned int* __restrict__ counts,
                                               float* __restrict__ out) {
    __shared__ __align__(16) unsigned short XH[M_TILE * ESTR];
    __shared__ __align__(16) unsigned short XL[M_TILE * ESTR];
    __shared__ __align__(16) unsigned short EH[128 * ESTR];
    __shared__ __align__(16) unsigned short EL[128 * ESTR];
    __shared__ __align__(16) float en_s[K_EMB];
    __shared__ __align__(16) float xs2[D];
    __shared__ int bks[M_TILE];
    __shared__ int flagl[M_TILE];
    __shared__ int nflag;
    __shared__ double rv[4];
    __shared__ int    rk[4];

    const int tid  = threadIdx.x;
    const int lane = tid & 63;
    const int w    = tid >> 6;
    const int hl   = lane >> 5;
    const int l31  = lane & 31;
    const int base = blockIdx.x * M_TILE;
    const int wrow = w * 32;

    if (tid == 0) nflag = 0;
    {
        float4 v = *reinterpret_cast<const float4*>(enorm32 + tid * 4);
        *reinterpret_cast<float4*>(&en_s[tid * 4]) = v;
    }
    {
        const float4* src = reinterpret_cast<const float4*>(in + (size_t)base * D);
#pragma unroll
        for (int i = 0; i < 8; ++i) {
            int lin = i * 256 + tid;
            float4 v = src[lin];
            int row = lin >> 4, c4 = lin & 15;
            ushort4 h, l;
            h.x = f2bf_rne(v.x); l.x = f2bf_rne(v.x - bf2f(h.x));
            h.y = f2bf_rne(v.y); l.y = f2bf_rne(v.y - bf2f(h.y));
            h.z = f2bf_rne(v.z); l.z = f2bf_rne(v.z - bf2f(h.z));
            h.w = f2bf_rne(v.w); l.w = f2bf_rne(v.w - bf2f(h.w));
            *reinterpret_cast<ushort4*>(&XH[row * ESTR + c4 * 4]) = h;
            *reinterpret_cast<ushort4*>(&XL[row * ESTR + c4 * 4]) = l;
        }
    }
    __syncthreads();

    bf16x8 AH[4], AL[4];
    {
        const unsigned short* xh = &XH[(wrow + l31) * ESTR + hl * 8];
        const unsigned short* xl = &XL[(wrow + l31) * ESTR + hl * 8];
#pragma unroll
        for (int kb = 0; kb < 4; ++kb) {
            AH[kb] = *reinterpret_cast<const bf16x8*>(xh + kb * 16);
            AL[kb] = *reinterpret_cast<const bf16x8*>(xl + kb * 16);
        }
    }

    float b1[16], b2[16]; int k1[16];
#pragma unroll
    for (int r = 0; r < 16; ++r) { b1[r] = 1e30f; b2[r] = 1e30f; k1[r] = 0; }

#pragma unroll 1
    for (int ch = 0; ch < K_EMB / 128; ++ch) {
        __syncthreads();
        {
            const float4* esrc = reinterpret_cast<const float4*>(emb + (size_t)ch * 128 * D);
#pragma unroll
            for (int i = 0; i < 8; ++i) {
                int lin = i * 256 + tid;
                float4 v = esrc[lin];
                int row = lin >> 4, c4 = lin & 15;
                ushort4 h, l;
                h.x = f2bf_rne(v.x); l.x = f2bf_rne(v.x - bf2f(h.x));
                h.y = f2bf_rne(v.y); l.y = f2bf_rne(v.y - bf2f(h.y));
                h.z = f2bf_rne(v.z); l.z = f2bf_rne(v.z - bf2f(h.z));
                h.w = f2bf_rne(v.w); l.w = f2bf_rne(v.w - bf2f(h.w));
                *reinterpret_cast<ushort4*>(&EH[row * ESTR + c4 * 4]) = h;
                *reinterpret_cast<ushort4*>(&EL[row * ESTR + c4 * 4]) = l;
            }
        }
        __syncthreads();

#pragma unroll 1
        for (int sub = 0; sub < 4; ++sub) {
            const unsigned short* eh = &EH[(sub * 32 + l31) * ESTR + hl * 8];
            const unsigned short* el = &EL[(sub * 32 + l31) * ESTR + hl * 8];
            bf16x8 BH[4], BL[4];
#pragma unroll
            for (int kb = 0; kb < 4; ++kb) {
                BH[kb] = *reinterpret_cast<const bf16x8*>(eh + kb * 16);
                BL[kb] = *reinterpret_cast<const bf16x8*>(el + kb * 16);
            }
            f32x16 acc = {};
#pragma unroll
            for (int kb = 0; kb < 4; ++kb)
                acc = __builtin_amdgcn_mfma_f32_32x32x16_bf16(AH[kb], BH[kb], acc, 0, 0, 0);
#pragma unroll
            for (int kb = 0; kb < 4; ++kb)
                acc = __builtin_amdgcn_mfma_f32_32x32x16_bf16(AH[kb], BL[kb], acc, 0, 0, 0);
#pragma unroll
            for (int kb = 0; kb < 4; ++kb)
                acc = __builtin_amdgcn_mfma_f32_32x32x16_bf16(AL[kb], BH[kb], acc, 0, 0, 0);

            int kg = ch * 128 + sub * 32 + l31;
            float en = en_s[kg];
#pragma unroll
            for (int r = 0; r < 16; ++r) {
                float s = fmaf(-2.f, acc[r], en);
                if (s < b1[r]) { b2[r] = b1[r]; b1[r] = s; k1[r] = kg; }
                else if (s < b2[r]) b2[r] = s;
            }
            asm volatile("" ::: "memory");
        }
    }

#pragma unroll
    for (int r = 0; r < 16; ++r) {
        float v = b1[r], v2 = b2[r]; int kk = k1[r];
#pragma unroll
        for (int off = 16; off >= 1; off >>= 1) {
            float ov  = __shfl_xor(v,  off, 64);
            int   ok  = __shfl_xor(kk, off, 64);
            float ov2 = __shfl_xor(v2, off, 64);
            bool win = (ov < v) || (ov == v && ok < kk);
            float loser = win ? v : ov;
            v2 = fminf(fminf(v2, ov2), loser);
            if (win) { v = ov; kk = ok; }
        }
        if (l31 == 0) {
            int row = wrow + (r & 3) + 8 * (r >> 2) + 4 * hl;
            bks[row] = kk;
            if (v2 - v < 2e-5f) { int p = atomicAdd(&nflag, 1); flagl[p] = row; }
        }
    }
    {
        float* ep = out + ENC_OFF + (size_t)base * K_EMB;
        float4 z = make_float4(0.f, 0.f, 0.f, 0.f);
        float4* ap = reinterpret_cast<float4*>(ep + 3);
        for (int i = tid; i < 32767; i += 256) ap[i] = z;
        if (tid == 0) { ep[0] = 0.f; ep[1] = 0.f; ep[2] = 0.f; ep[131071] = 0.f; }
    }
    __syncthreads();

    int nf = nflag;
#pragma unroll 1
    for (int fi = 0; fi < nf; ++fi) {
        int row = flagl[fi];
        if (tid < 16)
            *reinterpret_cast<float4*>(&xs2[tid * 4]) =
                reinterpret_cast<const float4*>(in + (size_t)(base + row) * D)[tid];
        __syncthreads();
        double bv = 1e300; int bk = 0;
#pragma unroll 1
        for (int c = 0; c < 4; ++c) {
            int k = tid * 4 + c;
            const float4* er = reinterpret_cast<const float4*>(emb + (size_t)k * D);
            double dot = 0.0, en = 0.0;
#pragma unroll 4
            for (int i = 0; i < 16; ++i) {
                float4 ev = er[i];
                float4 xv = *reinterpret_cast<const float4*>(&xs2[i * 4]);
                double e0 = ev.x, e1 = ev.y, e2 = ev.z, e3 = ev.w;
                en  = fma(e0, e0, en);  en  = fma(e1, e1, en);
                en  = fma(e2, e2, en);  en  = fma(e3, e3, en);
                dot = fma((double)xv.x, e0, dot); dot = fma((double)xv.y, e1, dot);
                dot = fma((double)xv.z, e2, dot); dot = fma((double)xv.w, e3, dot);
            }
            double s = fma(-2.0, dot, en);
            if (s < bv) { bv = s; bk = k; }
        }
        {
            double v = bv; int kk = bk;
#pragma unroll
            for (int off = 32; off >= 1; off >>= 1) {
                double ov = __shfl_xor(v, off, 64);
                int    ok = __shfl_xor(kk, off, 64);
                if (ov < v || (ov == v && ok < kk)) { v = ov; kk = ok; }
            }
            if (lane == 0) { rv[w] = v; rk[w] = kk; }
        }
        __syncthreads();
        if (tid == 0) {
            double v = rv[0]; int kk = rk[0];
#pragma unroll
            for (int x = 1; x < 4; ++x) {
                double ov = rv[x]; int ok = rk[x];
                if (ov < v || (ov == v && ok < kk)) { v = ov; kk = ok; }
            }
            bks[row] = kk;
        }
        __syncthreads();
    }

    if (tid < M_TILE) {
        int kk = bks[tid];
        atomicAdd(&counts[kk], 1u);
        out[ENC_OFF + (size_t)(base + tid) * K_EMB + kk] = 1.0f;
    }
    {
        int row = tid >> 1;
        int p   = tid & 1;
        int kk  = bks[row];
        const float4* er = reinterpret_cast<const float4*>(emb + (size_t)kk * D);
        float4* o1 = reinterpret_cast<float4*>(out + Q_ST_OFF + (size_t)(base + row) * D);
        float4* o2 = reinterpret_cast<float4*>(out + Q_OR_OFF + (size_t)(base + row) * D);
#pragma unroll
        for (int i = 0; i < 8; ++i) {
            float4 v = er[p * 8 + i];
            o1[p * 8 + i] = v;
            o2[p * 8 + i] = v;
        }
    }
}

extern "C" void kernel_launch(void* const* d_in, const int* in_sizes, int n_in,
                              void* d_out, int out_size, void* d_ws, size_t ws_size,
                              hipStream_t stream) {
    const float* in  = (const float*)d_in[0];
    const float* emb = (const float*)d_in[1];
    float* out = (float*)d_out;
    unsigned int* counts    = (unsigned int*)((char*)d_ws + WS_COUNTS);
    unsigned int* flagcount = (unsigned int*)((char*)d_ws + WS_FLAGCNT);
    float*        enorm32   = (float*)((char*)d_ws + WS_ENORM);

    if (ws_size >= WS_NEEDED) {
        int*            bks_g   = (int*)((char*)d_ws + WS_BKS);
        unsigned short* esplit  = (unsigned short*)((char*)d_ws + WS_ESPLIT);
        int*            flaglist= (int*)((char*)d_ws + WS_FLAGS);
        int flagcap = (int)((ws_size - WS_FLAGS) / 4);
        if (flagcap > N_ROWS) flagcap = N_ROWS;

        hipMemsetAsync(d_ws, 0, 8192, stream);   // counts + flagcount
        prep_kernel<<<4, 256, 0, stream>>>(emb, enorm32, esplit);
        vq_fused<<<N_ROWS / M_TILE, 256, 0, stream>>>(in, emb, esplit, enorm32, counts,
                                                      flagcount, flaglist, flagcap,
                                                      bks_g, out);
        rescore_kernel<<<1024, 256, 0, stream>>>(in, emb, flagcount, flaglist, flagcap,
                                                 counts, bks_g, out);
        perp_kernel<<<1, 1024, 0, stream>>>(counts, out + PERP_OFF);
    } else {
        hipMemsetAsync(d_ws, 0, 4096, stream);   // counts
        enorm32_kernel<<<K_EMB / 256, 256, 0, stream>>>(emb, enorm32);
        vq_mono<<<N_ROWS / M_TILE, 256, 0, stream>>>(in, emb, enorm32, counts, out);
        perp_kernel<<<1, 1024, 0, stream>>>(counts, out + PERP_OFF);
    }
}

// Round 9
// 752.276 us; speedup vs baseline: 1.2680x; 1.2175x over previous
//
#include <hip/hip_runtime.h>
#include <math.h>

// inputs [32,64,64,64] f32, embedding [1024,64] f32
#define N_ROWS 131072
#define D      64
#define K_EMB  1024
#define M_TILE 128          // rows per block (4 waves x 32)
#define KC     64           // codes per staged chunk
#define ESTR   72           // padded row stride (ushorts) in esplit/LDS

// Output layout (floats): q_st | q_orig | perplexity | encodings
#define Q_ST_OFF 0
#define Q_OR_OFF 8388608
#define PERP_OFF 16777216
#define ENC_OFF  16777217   // odd -> encodings region only 4B-aligned

// ws layout (main path): [0,4096) uint counts[1024]; [4096,8192) float mhn[1024] (-||e||^2/2);
//                        [8192,303104) ushort esplit[16][2][64][72]
#define WS_MHN     4096
#define WS_ESPLIT  8192
#define WS_NEEDED  303104

typedef __attribute__((ext_vector_type(8)))  short bf16x8;
typedef __attribute__((ext_vector_type(16))) float f32x16;

__device__ __forceinline__ unsigned short f2bf_rne(float f) {
    unsigned int u = __float_as_uint(f);
    unsigned int r = u + 0x7fffu + ((u >> 16) & 1u);
    return (unsigned short)(r >> 16);
}
__device__ __forceinline__ float bf2f(unsigned short h) {
    return __uint_as_float(((unsigned int)h) << 16);
}

// ---------- prep: -||e||^2/2 + bf16 hi/lo split of embedding (once) ----------
__global__ __launch_bounds__(256) void prep_kernel(const float* __restrict__ emb,
                                                   float* __restrict__ mhn,
                                                   unsigned short* __restrict__ esplit) {
    int k = blockIdx.x * 256 + threadIdx.x;           // code row 0..1023
    if (k >= K_EMB) return;
    const float4* row = reinterpret_cast<const float4*>(emb + (size_t)k * D);
    unsigned short* hb = esplit + (size_t)(k >> 6) * (2 * 64 * ESTR) + (k & 63) * ESTR;
    unsigned short* lb = hb + 64 * ESTR;
    float s = 0.f;
#pragma unroll
    for (int i = 0; i < 16; ++i) {
        float4 v = row[i];
        s = fmaf(v.x, v.x, s); s = fmaf(v.y, v.y, s);
        s = fmaf(v.z, v.z, s); s = fmaf(v.w, v.w, s);
        ushort4 h, l;
        h.x = f2bf_rne(v.x); l.x = f2bf_rne(v.x - bf2f(h.x));
        h.y = f2bf_rne(v.y); l.y = f2bf_rne(v.y - bf2f(h.y));
        h.z = f2bf_rne(v.z); l.z = f2bf_rne(v.z - bf2f(h.z));
        h.w = f2bf_rne(v.w); l.w = f2bf_rne(v.w - bf2f(h.w));
        *reinterpret_cast<ushort4*>(hb + i * 4) = h;
        *reinterpret_cast<ushort4*>(lb + i * 4) = l;
    }
    mhn[k] = -0.5f * s;
}

// ---------- fused: MFMA argmin (max of x.e - ||e||^2/2) + all output writes ----------
__global__ __launch_bounds__(256) void vq_fused(const float* __restrict__ in,
                                                const float* __restrict__ emb,
                                                const unsigned short* __restrict__ esplit,
                                                const float* __restrict__ mhn,
                                                unsigned int* __restrict__ counts,
                                                float* __restrict__ out) {
    __shared__ __align__(16) unsigned short EHL[2][64][ESTR];  // [hi/lo][code][dim]
    __shared__ __align__(16) float mhn_s[K_EMB];
    __shared__ int bks_s[M_TILE];

    const int tid  = threadIdx.x;
    const int lane = tid & 63;
    const int w    = tid >> 6;         // wave 0..3
    const int hl   = lane >> 5;        // k-half select
    const int l31  = lane & 31;
    const int base = blockIdx.x * M_TILE;
    const int wrow = w * 32;

    // stage -||e||^2/2 values
    {
        float4 v = *reinterpret_cast<const float4*>(mhn + tid * 4);
        *reinterpret_cast<float4*>(&mhn_s[tid * 4]) = v;
    }

    // A fragments direct from global: row = base+wrow+l31, k-seg = kb*16 + hl*8
    bf16x8 AH[4], AL[4];
    {
        const float* xrow = in + (size_t)(base + wrow + l31) * D + hl * 8;
#pragma unroll
        for (int kb = 0; kb < 4; ++kb) {
            float4 a = *reinterpret_cast<const float4*>(xrow + kb * 16);
            float4 b = *reinterpret_cast<const float4*>(xrow + kb * 16 + 4);
            float f[8] = {a.x, a.y, a.z, a.w, b.x, b.y, b.z, b.w};
            union { bf16x8 v; unsigned short u[8]; } H, L;
#pragma unroll
            for (int j = 0; j < 8; ++j) {
                H.u[j] = f2bf_rne(f[j]);
                L.u[j] = f2bf_rne(f[j] - bf2f(H.u[j]));
            }
            AH[kb] = H.v; AL[kb] = L.v;
        }
    }

    float b1[16]; int k1[16];
#pragma unroll
    for (int r = 0; r < 16; ++r) { b1[r] = -1e30f; k1[r] = 0; }

    // staging: load chunk to regs early, ds_write late; single LDS buffer
    uint4 st[5];
    const uint4* src0 = reinterpret_cast<const uint4*>(esplit);  // chunk = 1152 uint4
#pragma unroll
    for (int i = 0; i < 5; ++i) {
        int idx = i * 256 + tid;
        if (idx < 1152) st[i] = src0[idx];
    }

#pragma unroll 1
    for (int ch = 0; ch < K_EMB / KC; ++ch) {
        {   // write staged chunk into LDS
            uint4* d = reinterpret_cast<uint4*>(&EHL[0][0][0]);
#pragma unroll
            for (int i = 0; i < 5; ++i) {
                int idx = i * 256 + tid;
                if (idx < 1152) d[idx] = st[i];
            }
        }
        __syncthreads();
        if (ch < 15) {   // prefetch next chunk (completes under compute)
            const uint4* s = src0 + (ch + 1) * 1152;
#pragma unroll
            for (int i = 0; i < 5; ++i) {
                int idx = i * 256 + tid;
                if (idx < 1152) st[i] = s[idx];
            }
        }

#pragma unroll 1
        for (int sub = 0; sub < 2; ++sub) {
            const unsigned short* eh = &EHL[0][sub * 32 + l31][hl * 8];
            const unsigned short* el = &EHL[1][sub * 32 + l31][hl * 8];
            bf16x8 BH[4], BL[4];
#pragma unroll
            for (int kb = 0; kb < 4; ++kb) {
                BH[kb] = *reinterpret_cast<const bf16x8*>(eh + kb * 16);
                BL[kb] = *reinterpret_cast<const bf16x8*>(el + kb * 16);
            }
            int kg = ch * KC + sub * 32 + l31;          // this lane's code (column)
            float mh = mhn_s[kg];
            f32x16 acc;
#pragma unroll
            for (int r = 0; r < 16; ++r) acc[r] = mh;   // C-init = -||e||^2/2
#pragma unroll
            for (int kb = 0; kb < 4; ++kb)
                acc = __builtin_amdgcn_mfma_f32_32x32x16_bf16(AH[kb], BH[kb], acc, 0, 0, 0);
#pragma unroll
            for (int kb = 0; kb < 4; ++kb)
                acc = __builtin_amdgcn_mfma_f32_32x32x16_bf16(AH[kb], BL[kb], acc, 0, 0, 0);
#pragma unroll
            for (int kb = 0; kb < 4; ++kb)
                acc = __builtin_amdgcn_mfma_f32_32x32x16_bf16(AL[kb], BH[kb], acc, 0, 0, 0);

#pragma unroll
            for (int r = 0; r < 16; ++r) {
                if (acc[r] > b1[r]) { b1[r] = acc[r]; k1[r] = kg; }
            }
        }
        __syncthreads();
    }

    // argmax reduce across the 32 column-lanes
#pragma unroll
    for (int r = 0; r < 16; ++r) {
        float v = b1[r]; int kk = k1[r];
#pragma unroll
        for (int off = 16; off >= 1; off >>= 1) {
            float ov = __shfl_xor(v,  off, 64);
            int   ok = __shfl_xor(kk, off, 64);
            if ((ov > v) || (ov == v && ok < kk)) { v = ov; kk = ok; }
        }
        if (l31 == 0) {
            int row = wrow + (r & 3) + 8 * (r >> 2) + 4 * hl;  // C-layout row
            bks_s[row] = kk;
        }
    }
    __syncthreads();

    if (tid < M_TILE) atomicAdd(&counts[bks_s[tid]], 1u);

    // ---- q_st / q_orig: gathered from emb via bks_s ----
    {
        const float4* embF4 = reinterpret_cast<const float4*>(emb);
        float4* o1 = reinterpret_cast<float4*>(out + Q_ST_OFF + (size_t)base * D);
        float4* o2 = reinterpret_cast<float4*>(out + Q_OR_OFF + (size_t)base * D);
#pragma unroll 1
        for (int i = 0; i < 8; ++i) {
            int f4q = i * 256 + tid;          // 0..2047
            int row = f4q >> 4, c4 = f4q & 15;
            float4 v = embF4[(size_t)bks_s[row] * 16 + c4];
            o1[f4q] = v;
            o2[f4q] = v;
        }
    }

    // ---- encodings: zero-fill + scatter (region 4B-aligned only) ----
    {
        float* ep = out + ENC_OFF + (size_t)base * K_EMB;   // float idx ≡ 1 (mod 4)
        float4 z = make_float4(0.f, 0.f, 0.f, 0.f);
        float4* ap = reinterpret_cast<float4*>(ep + 3);     // 16B-aligned
#pragma unroll 1
        for (int i = tid; i < 32767; i += 256) ap[i] = z;
        if (tid == 0) {
            ep[0] = 0.f; ep[1] = 0.f; ep[2] = 0.f; ep[131071] = 0.f;
        }
    }
    __syncthreads();   // zeros complete before scatter
    if (tid < M_TILE) {
        out[ENC_OFF + (size_t)(base + tid) * K_EMB + bks_s[tid]] = 1.0f;
    }
}

__global__ __launch_bounds__(1024) void perp_kernel(const unsigned int* __restrict__ counts,
                                                    float* __restrict__ out_perp) {
    const int k = threadIdx.x;
    double p = (double)counts[k] * (1.0 / (double)N_ROWS);
    double t = p * log(p + 1e-10);
#pragma unroll
    for (int off = 32; off >= 1; off >>= 1) t += __shfl_down(t, off, 64);
    __shared__ double red[16];
    if ((k & 63) == 0) red[k >> 6] = t;
    __syncthreads();
    if (k < 16) {
        double s = red[k];
#pragma unroll
        for (int off = 8; off >= 1; off >>= 1) s += __shfl_down(s, off, 16);
        if (k == 0) out_perp[0] = (float)exp(-s);
    }
}

// ================= fallback (tiny ws): self-contained monolith =================
__global__ __launch_bounds__(256) void enorm32_kernel(const float* __restrict__ emb,
                                                      float* __restrict__ enorm) {
    int k = blockIdx.x * 256 + threadIdx.x;
    const float4* row = reinterpret_cast<const float4*>(emb + (size_t)k * D);
    float s = 0.f;
#pragma unroll
    for (int i = 0; i < 16; ++i) {
        float4 v = row[i];
        s = fmaf(v.x, v.x, s); s = fmaf(v.y, v.y, s);
        s = fmaf(v.z, v.z, s); s = fmaf(v.w, v.w, s);
    }
    enorm[k] = s;
}

__global__ __launch_bounds__(256) void vq_mono(const float* __restrict__ in,
                                               const float* __restrict__ emb,
                                               const float* __restrict__ enorm32,
                                               unsigned int* __restrict__ counts,
                                               float* __restrict__ out) {
    __shared__ __align__(16) unsigned short XH[M_TILE * ESTR];
    __shared__ __align__(16) unsigned short XL[M_TILE * ESTR];
    __shared__ __align__(16) unsigned short EH[128 * ESTR];
    __shared__ __align__(16) unsigned short EL[128 * ESTR];
    __shared__ __align__(16) float en_s[K_EMB];
    __shared__ int bks[M_TILE];

    const int tid  = threadIdx.x;
    const int lane = tid & 63;
    const int w    = tid >> 6;
    const int hl   = lane >> 5;
    const int l31  = lane & 31;
    const int base = blockIdx.x * M_TILE;
    const int wrow = w * 32;

    {
        float4 v = *reinterpret_cast<const float4*>(enorm32 + tid * 4);
        *reinterpret_cast<float4*>(&en_s[tid * 4]) = v;
    }
    {
        const float4* src = reinterpret_cast<const float4*>(in + (size_t)base * D);
#pragma unroll
        for (int i = 0; i < 8; ++i) {
            int lin = i * 256 + tid;
            float4 v = src[lin];
            int row = lin >> 4, c4 = lin & 15;
            ushort4 h, l;
            h.x = f2bf_rne(v.x); l.x = f2bf_rne(v.x - bf2f(h.x));
            h.y = f2bf_rne(v.y); l.y = f2bf_rne(v.y - bf2f(h.y));
            h.z = f2bf_rne(v.z); l.z = f2bf_rne(v.z - bf2f(h.z));
            h.w = f2bf_rne(v.w); l.w = f2bf_rne(v.w - bf2f(h.w));
            *reinterpret_cast<ushort4*>(&XH[row * ESTR + c4 * 4]) = h;
            *reinterpret_cast<ushort4*>(&XL[row * ESTR + c4 * 4]) = l;
        }
    }
    __syncthreads();

    bf16x8 AH[4], AL[4];
    {
        const unsigned short* xh = &XH[(wrow + l31) * ESTR + hl * 8];
        const unsigned short* xl = &XL[(wrow + l31) * ESTR + hl * 8];
#pragma unroll
        for (int kb = 0; kb < 4; ++kb) {
            AH[kb] = *reinterpret_cast<const bf16x8*>(xh + kb * 16);
            AL[kb] = *reinterpret_cast<const bf16x8*>(xl + kb * 16);
        }
    }

    float b1[16]; int k1[16];
#pragma unroll
    for (int r = 0; r < 16; ++r) { b1[r] = 1e30f; k1[r] = 0; }

#pragma unroll 1
    for (int ch = 0; ch < K_EMB / 128; ++ch) {
        __syncthreads();
        {
            const float4* esrc = reinterpret_cast<const float4*>(emb + (size_t)ch * 128 * D);
#pragma unroll
            for (int i = 0; i < 8; ++i) {
                int lin = i * 256 + tid;
                float4 v = esrc[lin];
                int row = lin >> 4, c4 = lin & 15;
                ushort4 h, l;
                h.x = f2bf_rne(v.x); l.x = f2bf_rne(v.x - bf2f(h.x));
                h.y = f2bf_rne(v.y); l.y = f2bf_rne(v.y - bf2f(h.y));
                h.z = f2bf_rne(v.z); l.z = f2bf_rne(v.z - bf2f(h.z));
                h.w = f2bf_rne(v.w); l.w = f2bf_rne(v.w - bf2f(h.w));
                *reinterpret_cast<ushort4*>(&EH[row * ESTR + c4 * 4]) = h;
                *reinterpret_cast<ushort4*>(&EL[row * ESTR + c4 * 4]) = l;
            }
        }
        __syncthreads();

#pragma unroll 1
        for (int sub = 0; sub < 4; ++sub) {
            const unsigned short* eh = &EH[(sub * 32 + l31) * ESTR + hl * 8];
            const unsigned short* el = &EL[(sub * 32 + l31) * ESTR + hl * 8];
            bf16x8 BH[4], BL[4];
#pragma unroll
            for (int kb = 0; kb < 4; ++kb) {
                BH[kb] = *reinterpret_cast<const bf16x8*>(eh + kb * 16);
                BL[kb] = *reinterpret_cast<const bf16x8*>(el + kb * 16);
            }
            f32x16 acc = {};
#pragma unroll
            for (int kb = 0; kb < 4; ++kb)
                acc = __builtin_amdgcn_mfma_f32_32x32x16_bf16(AH[kb], BH[kb], acc, 0, 0, 0);
#pragma unroll
            for (int kb = 0; kb < 4; ++kb)
                acc = __builtin_amdgcn_mfma_f32_32x32x16_bf16(AH[kb], BL[kb], acc, 0, 0, 0);
#pragma unroll
            for (int kb = 0; kb < 4; ++kb)
                acc = __builtin_amdgcn_mfma_f32_32x32x16_bf16(AL[kb], BH[kb], acc, 0, 0, 0);

            int kg = ch * 128 + sub * 32 + l31;
            float en = en_s[kg];
#pragma unroll
            for (int r = 0; r < 16; ++r) {
                float s = fmaf(-2.f, acc[r], en);
                if (s < b1[r]) { b1[r] = s; k1[r] = kg; }
            }
            asm volatile("" ::: "memory");
        }
    }

#pragma unroll
    for (int r = 0; r < 16; ++r) {
        float v = b1[r]; int kk = k1[r];
#pragma unroll
        for (int off = 16; off >= 1; off >>= 1) {
            float ov = __shfl_xor(v,  off, 64);
            int   ok = __shfl_xor(kk, off, 64);
            if ((ov < v) || (ov == v && ok < kk)) { v = ov; kk = ok; }
        }
        if (l31 == 0) bks[wrow + (r & 3) + 8 * (r >> 2) + 4 * hl] = kk;
    }
    {
        float* ep = out + ENC_OFF + (size_t)base * K_EMB;
        float4 z = make_float4(0.f, 0.f, 0.f, 0.f);
        float4* ap = reinterpret_cast<float4*>(ep + 3);
        for (int i = tid; i < 32767; i += 256) ap[i] = z;
        if (tid == 0) { ep[0] = 0.f; ep[1] = 0.f; ep[2] = 0.f; ep[131071] = 0.f; }
    }
    __syncthreads();

    if (tid < M_TILE) {
        int kk = bks[tid];
        atomicAdd(&counts[kk], 1u);
        out[ENC_OFF + (size_t)(base + tid) * K_EMB + kk] = 1.0f;
    }
    {
        int row = tid >> 1;
        int p   = tid & 1;
        int kk  = bks[row];
        const float4* er = reinterpret_cast<const float4*>(emb + (size_t)kk * D);
        float4* o1 = reinterpret_cast<float4*>(out + Q_ST_OFF + (size_t)(base + row) * D);
        float4* o2 = reinterpret_cast<float4*>(out + Q_OR_OFF + (size_t)(base + row) * D);
#pragma unroll
        for (int i = 0; i < 8; ++i) {
            float4 v = er[p * 8 + i];
            o1[p * 8 + i] = v;
            o2[p * 8 + i] = v;
        }
    }
}

extern "C" void kernel_launch(void* const* d_in, const int* in_sizes, int n_in,
                              void* d_out, int out_size, void* d_ws, size_t ws_size,
                              hipStream_t stream) {
    const float* in  = (const float*)d_in[0];
    const float* emb = (const float*)d_in[1];
    float* out = (float*)d_out;
    unsigned int* counts = (unsigned int*)d_ws;

    hipMemsetAsync(d_ws, 0, 4096, stream);   // counts
    if (ws_size >= WS_NEEDED) {
        float*          mhn    = (float*)((char*)d_ws + WS_MHN);
        unsigned short* esplit = (unsigned short*)((char*)d_ws + WS_ESPLIT);
        prep_kernel<<<4, 256, 0, stream>>>(emb, mhn, esplit);
        vq_fused<<<N_ROWS / M_TILE, 256, 0, stream>>>(in, emb, esplit, mhn, counts, out);
    } else {
        float* enorm32 = (float*)((char*)d_ws + WS_MHN);
        enorm32_kernel<<<K_EMB / 256, 256, 0, stream>>>(emb, enorm32);
        vq_mono<<<N_ROWS / M_TILE, 256, 0, stream>>>(in, emb, enorm32, counts, out);
    }
    perp_kernel<<<1, 1024, 0, stream>>>(counts, out + PERP_OFF);
}